// Round 7
// baseline (9497.305 us; speedup 1.0000x reference)
//
#include <hip/hip_runtime.h>
#include <math.h>

#define B_  64
#define T_  1024
#define I_  512
#define O_  512
#define NZ  2048      // 4*O
#define KW  1024      // W row stride (I+O)
#define EPS 1e-5f

#define SREC 32       // recurrent grid: 32 blocks, each owns 16 o-values
#define OSL  16

typedef short bf8_t  __attribute__((ext_vector_type(8)));
typedef float f32x4  __attribute__((ext_vector_type(4)));
typedef unsigned uint4v __attribute__((ext_vector_type(4)));

__device__ __forceinline__ unsigned short f2bf(float f) {
  union { float f; unsigned u; } v; v.f = f;
  unsigned r = v.u + 0x7FFFu + ((v.u >> 16) & 1u);   // RNE
  return (unsigned short)(r >> 16);
}
__device__ __forceinline__ float bf2f(unsigned short b) {
  union { unsigned u; float f; } v; v.u = ((unsigned)b) << 16;
  return v.f;
}

// ---------------------------------------------------------------------------
// K0: zero flag slots, init h (bf16) from init_hx
// ---------------------------------------------------------------------------
__global__ __launch_bounds__(256) void init_all(
    const float* __restrict__ init_hx,
    unsigned short* __restrict__ h, unsigned* __restrict__ sync) {
  int idx = blockIdx.x * 256 + threadIdx.x;
  if (idx < 2048) sync[idx] = 0u;
  if (idx < B_ * O_) h[idx] = f2bf(init_hx[idx & (O_ - 1)]);
}

// ---------------------------------------------------------------------------
// K0b: one-time Wx (rows 0..2047, k 0..511) f32 -> bf16.
// ---------------------------------------------------------------------------
__global__ __launch_bounds__(256) void wx_bf16(
    const float* __restrict__ W, unsigned short* __restrict__ Wbf) {
  int idx = blockIdx.x * 256 + threadIdx.x;   // one float4 each; 262144 total
  int n  = idx >> 7;
  int k4 = (idx & 127) * 4;
  float4 v = *(const float4*)(W + (size_t)n * KW + k4);
  unsigned short* d = Wbf + (size_t)n * 512 + k4;
  d[0] = f2bf(v.x); d[1] = f2bf(v.y); d[2] = f2bf(v.z); d[3] = f2bf(v.w);
}

// ---------------------------------------------------------------------------
// K1: zx = x @ Wx^T with LDS x-reuse (validated R3) + LDS-staged C-write.
// R7 change: the old epilogue issued 512 scalar 2B global stores per thread
// (VMEM-issue-bound). Now: stage 64x64 bf16 tile in LDS, store 2 coalesced
// dwordx4 per thread per nblk (64 wide stores/thread total).
// ---------------------------------------------------------------------------
__global__ __launch_bounds__(256) void zx_gemm(
    const float* __restrict__ x, const unsigned short* __restrict__ Wbf,
    unsigned short* __restrict__ zx) {
  __shared__ unsigned short xl[64 * 520];
  __shared__ unsigned short cst[64 * 72];   // 64x64 out tile, stride 72 (144B rows, 16B-aligned)

  const int tid  = threadIdx.x;
  const int w    = tid >> 6;
  const int lane = tid & 63;
  const int q    = lane >> 4;
  const int col  = lane & 15;
  const int m0   = blockIdx.x * 64;

  for (int e4 = tid; e4 < 64 * 128; e4 += 256) {
    int r  = e4 >> 7;
    int k4 = (e4 & 127) * 4;
    float4 v = *(const float4*)(x + (size_t)(m0 + r) * I_ + k4);
    unsigned short* d = &xl[r * 520 + k4];
    d[0] = f2bf(v.x); d[1] = f2bf(v.y); d[2] = f2bf(v.z); d[3] = f2bf(v.w);
  }
  __syncthreads();

  const unsigned short* __restrict__ arow = &xl[(16 * w + col) * 520];
  const int crow = tid >> 2;            // store phase: row 0..63
  const int cc0  = (tid & 3) * 16;      // 16-short chunk

  for (int nblk = 0; nblk < 32; ++nblk) {
    const int n0 = nblk * 64;
    f32x4 acc[4];
    #pragma unroll
    for (int i = 0; i < 4; ++i) acc[i] = (f32x4){0.f, 0.f, 0.f, 0.f};

    #pragma unroll
    for (int ks = 0; ks < 16; ++ks) {
      const int k0 = ks * 32 + q * 8;
      bf8_t af = *(const bf8_t*)(arow + k0);
      #pragma unroll
      for (int nt = 0; nt < 4; ++nt) {
        bf8_t bfr = *(const bf8_t*)(Wbf + (size_t)(n0 + nt * 16 + col) * 512 + k0);
        acc[nt] = __builtin_amdgcn_mfma_f32_16x16x32_bf16(af, bfr, acc[nt], 0, 0, 0);
      }
    }
    // C/D layout: col = lane&15, row = (lane>>4)*4 + reg  [verified m89]
    __syncthreads();   // cst free (prev iter's readers done)
    #pragma unroll
    for (int nt = 0; nt < 4; ++nt)
      #pragma unroll
      for (int r = 0; r < 4; ++r)
        cst[(16 * w + 4 * q + r) * 72 + nt * 16 + col] = f2bf(acc[nt][r]);
    __syncthreads();
    {
      const uint4v* srcp = (const uint4v*)&cst[crow * 72 + cc0];
      uint4v v0 = srcp[0], v1 = srcp[1];
      uint4v* dst = (uint4v*)&zx[(size_t)(m0 + crow) * NZ + n0 + cc0];
      dst[0] = v0; dst[1] = v1;
    }
  }
}

// ---------------------------------------------------------------------------
// K2: recurrent loop — EXACT R3 kernel (validated green, 8430 us).
// Sync: flag-array barrier, fence-free, agent-scope __hip_atomic (sc1).
//  - arrive: plain sc1 store of monotonic value to block-private flag line.
//  - poll: every thread loads flags[(tid&31)*16] -> one vector load per wave
//    gathers all 32 flags across 32 LLC lines in parallel.
//  - __syncthreads() before arrive drains vmcnt(0) for every wave (release).
//  - part8 s-major; distributed per-wave LN reduce via shfl.
//  - out stores + zx(t+1) prefetch in bar2's shadow (arrive -> work -> poll).
// ---------------------------------------------------------------------------
__global__ __launch_bounds__(256) void lstm_rec(
    const float* __restrict__ W, const float* __restrict__ gamma,
    const float* __restrict__ beta, const float* __restrict__ init_cx,
    const unsigned short* __restrict__ zx, unsigned short* __restrict__ h,
    unsigned long long* __restrict__ part8, float* __restrict__ out,
    unsigned* __restrict__ flags) {

  __shared__ unsigned short whlds[64 * 520];   // 64 rows (g*16+n'), pad 512->520

  const int tid  = threadIdx.x;
  const int w    = tid >> 6;
  const int lane = tid & 63;
  const int q    = lane >> 4;
  const int col  = lane & 15;
  const int s    = blockIdx.x;
  const int o    = s * OSL + col;

  // ---- stage Wh slice -> LDS (once)
  for (int e4 = tid; e4 < 64 * 128; e4 += 256) {
    int r  = e4 >> 7;            // row 0..63
    int k4 = (e4 & 127) * 4;     // k 0..508
    int g  = r >> 4, np = r & 15;
    const float4 v =
        *(const float4*)(W + (size_t)(512 * g + OSL * s + np) * KW + I_ + k4);
    unsigned short* d = &whlds[r * 520 + k4];
    d[0] = f2bf(v.x); d[1] = f2bf(v.y); d[2] = f2bf(v.z); d[3] = f2bf(v.w);
  }

  float gma[4], bta[4], c_reg[4];
  #pragma unroll
  for (int g = 0; g < 4; ++g) { gma[g] = gamma[g * O_ + o]; bta[g] = beta[g * O_ + o]; }
  { float c0 = init_cx[o];
    #pragma unroll
    for (int r = 0; r < 4; ++r) c_reg[r] = c0; }

  // ---- prologue: prefetch zx for t=0
  unsigned short zxl[16];
  #pragma unroll
  for (int g = 0; g < 4; ++g)
    #pragma unroll
    for (int r = 0; r < 4; ++r) {
      int b = 16 * w + 4 * q + r;
      zxl[g * 4 + r] = zx[((size_t)b * T_ + 0) * NZ + g * O_ + OSL * s + col];
    }

  __syncthreads();

  for (int t = 0; t < T_; ++t) {
    // ---- gather full h fragment set (sc1 read-through; fresh after bar2)
    unsigned long long araw[32];
    const unsigned short* hrow = h + (16 * w + col) * O_;
    #pragma unroll
    for (int ks = 0; ks < 16; ++ks) {
      const unsigned long long* p =
          (const unsigned long long*)(hrow + ks * 32 + q * 8);
      araw[2 * ks]     = __hip_atomic_load(p,     __ATOMIC_RELAXED, __HIP_MEMORY_SCOPE_AGENT);
      araw[2 * ks + 1] = __hip_atomic_load(p + 1, __ATOMIC_RELAXED, __HIP_MEMORY_SCOPE_AGENT);
    }

    // ---- z-slice = h @ Wh^T  (16x16x32 bf16 MFMA; wave w -> rows 16w..16w+15)
    f32x4 acc[4];
    #pragma unroll
    for (int g = 0; g < 4; ++g) acc[g] = (f32x4){0.f, 0.f, 0.f, 0.f};

    #pragma unroll
    for (int ks = 0; ks < 16; ++ks) {
      union { unsigned long long u[2]; bf8_t v; } au;
      au.u[0] = araw[2 * ks]; au.u[1] = araw[2 * ks + 1];
      #pragma unroll
      for (int g = 0; g < 4; ++g) {
        bf8_t bfr = *(const bf8_t*)(&whlds[(g * 16 + col) * 520 + ks * 32 + q * 8]);
        acc[g] = __builtin_amdgcn_mfma_f32_16x16x32_bf16(au.v, bfr, acc[g], 0, 0, 0);
      }
    }

    // ---- z = acc + zx; block-partial LN sums per batch row
    float z[16];
    float s1[4], s2[4];
    #pragma unroll
    for (int r = 0; r < 4; ++r) { s1[r] = 0.f; s2[r] = 0.f; }
    #pragma unroll
    for (int g = 0; g < 4; ++g)
      #pragma unroll
      for (int r = 0; r < 4; ++r) {
        float zv = acc[g][r] + bf2f(zxl[g * 4 + r]);
        z[g * 4 + r] = zv;
        s1[r] += zv;
        s2[r] += zv * zv;
      }
    #pragma unroll
    for (int m = 1; m < 16; m <<= 1) {
      #pragma unroll
      for (int r = 0; r < 4; ++r) {
        s1[r] += __shfl_xor(s1[r], m, 64);
        s2[r] += __shfl_xor(s2[r], m, 64);
      }
    }
    if (col == 0) {
      #pragma unroll
      for (int r = 0; r < 4; ++r) {
        int b = 16 * w + 4 * q + r;
        union { float f[2]; unsigned long long u; } pv;
        pv.f[0] = s1[r]; pv.f[1] = s2[r];
        __hip_atomic_store(&part8[(size_t)s * 64 + b], pv.u,
                           __ATOMIC_RELAXED, __HIP_MEMORY_SCOPE_AGENT);
      }
    }

    // ---- barrier 1: partials ready
    __syncthreads();   // drains vmcnt(0) for all waves -> partials at LLC
    {
      const unsigned tgt = 2u * (unsigned)t + 1u;
      if (tid == 0)
        __hip_atomic_store(&flags[s * 16], tgt,
                           __ATOMIC_RELAXED, __HIP_MEMORY_SCOPE_AGENT);
      const unsigned* fp = &flags[(tid & 31) * 16];
      while (__hip_atomic_load(fp, __ATOMIC_RELAXED, __HIP_MEMORY_SCOPE_AGENT) < tgt) {}
    }

    // ---- distributed LN reduce: lane owns brow = 16w+(lane&15); 8 s-chunks
    float S1 = 0.f, S2 = 0.f;
    {
      const int brow = 16 * w + (lane & 15);
      const int sbase = (lane >> 4) * 8;
      #pragma unroll
      for (int i = 0; i < 8; ++i) {
        union { float f[2]; unsigned long long u; } pv;
        pv.u = __hip_atomic_load(&part8[(size_t)(sbase + i) * 64 + brow],
                                 __ATOMIC_RELAXED, __HIP_MEMORY_SCOPE_AGENT);
        S1 += pv.f[0]; S2 += pv.f[1];
      }
    }
    S1 += __shfl_xor(S1, 16, 64); S2 += __shfl_xor(S2, 16, 64);
    S1 += __shfl_xor(S1, 32, 64); S2 += __shfl_xor(S2, 32, 64);
    float mean_l = S1 * (1.f / NZ);
    float rstd_l = rsqrtf(S2 * (1.f / NZ) - mean_l * mean_l + EPS);

    // ---- gates + state update (mean/rstd pulled from lane 4q+r)
    float hnl[4];
    #pragma unroll
    for (int r = 0; r < 4; ++r) {
      int b = 16 * w + 4 * q + r;
      float mean = __shfl(mean_l, 4 * q + r, 64);
      float rstd = __shfl(rstd_l, 4 * q + r, 64);
      float zn0 = (z[0 * 4 + r] - mean) * rstd * gma[0] + bta[0];
      float zn1 = (z[1 * 4 + r] - mean) * rstd * gma[1] + bta[1];
      float zn2 = (z[2 * 4 + r] - mean) * rstd * gma[2] + bta[2];
      float zn3 = (z[3 * 4 + r] - mean) * rstd * gma[3] + bta[3];
      float fg = 1.f / (1.f + expf(-zn0));
      float ig = 1.f / (1.f + expf(-zn1));
      float og = 1.f / (1.f + expf(-zn2));
      float gg = 0.5f * zn3 * (1.f + erff(zn3 * 0.70710678118654752f));
      float cn = fg * c_reg[r] + ig * gg;
      float hn = og * cn;
      c_reg[r] = cn;
      hnl[r] = hn;
      __hip_atomic_store(&h[b * O_ + o], f2bf(hn),
                         __ATOMIC_RELAXED, __HIP_MEMORY_SCOPE_AGENT);
    }

    // ---- barrier 2: h ready. out stores + zx prefetch live in the shadow.
    if (t + 1 < T_) {
      __syncthreads();   // drains vmcnt(0) -> h stores at LLC
      const unsigned tgt = 2u * (unsigned)t + 2u;
      if (tid == 0)
        __hip_atomic_store(&flags[s * 16], tgt,
                           __ATOMIC_RELAXED, __HIP_MEMORY_SCOPE_AGENT);
      #pragma unroll
      for (int r = 0; r < 4; ++r) {
        int b = 16 * w + 4 * q + r;
        out[((size_t)b * T_ + t) * O_ + o] = hnl[r];
      }
      #pragma unroll
      for (int g = 0; g < 4; ++g)
        #pragma unroll
        for (int r = 0; r < 4; ++r) {
          int b = 16 * w + 4 * q + r;
          zxl[g * 4 + r] =
              zx[((size_t)b * T_ + (t + 1)) * NZ + g * O_ + OSL * s + col];
        }
      const unsigned* fp = &flags[(tid & 31) * 16];
      while (__hip_atomic_load(fp, __ATOMIC_RELAXED, __HIP_MEMORY_SCOPE_AGENT) < tgt) {}
    } else {
      #pragma unroll
      for (int r = 0; r < 4; ++r) {
        int b = 16 * w + 4 * q + r;
        out[((size_t)b * T_ + t) * O_ + o] = hnl[r];
      }
    }
  }
}

// ---------------------------------------------------------------------------
extern "C" void kernel_launch(void* const* d_in, const int* in_sizes, int n_in,
                              void* d_out, int out_size, void* d_ws, size_t ws_size,
                              hipStream_t stream) {
  const float* x       = (const float*)d_in[0];
  const float* W       = (const float*)d_in[1];
  const float* gamma   = (const float*)d_in[2];
  const float* beta    = (const float*)d_in[3];
  const float* init_hx = (const float*)d_in[4];
  const float* init_cx = (const float*)d_in[5];
  float* out = (float*)d_out;
  (void)in_sizes; (void)n_in; (void)out_size; (void)ws_size;

  char* ws = (char*)d_ws;
  unsigned*           flags = (unsigned*)(ws);                        // 8 KB zeroed
  unsigned long long* part8 = (unsigned long long*)(ws + 8192);       // 16 KB
  unsigned short*     h     = (unsigned short*)(ws + 32768);          // 64 KB
  unsigned short*     Wbf   = (unsigned short*)(ws + (1 << 20));      // 2 MB
  unsigned short*     zx    = (unsigned short*)(ws + (4 << 20));      // 256 MB

  init_all<<<128, 256, 0, stream>>>(init_hx, h, flags);
  wx_bf16<<<1024, 256, 0, stream>>>(W, Wbf);
  zx_gemm<<<1024, 256, 0, stream>>>(x, Wbf, zx);
  lstm_rec<<<SREC, 256, 0, stream>>>(W, gamma, beta, init_cx, zx, h, part8, out, flags);
}